// Round 8
// baseline (160.433 us; speedup 1.0000x reference)
//
#include <hip/hip_runtime.h>

#define T_STEPS 256
#define IMG 512
#define HW (IMG * IMG)
#define TW 64                  // tile width
#define TH 8                   // tile height
#define ROWCHK 18              // real 16B chunks per halo row (cols -4..67)
#define ROWSTRIDE 21           // LDS slot stride per halo row (bank spread: gcd(21,8)=1)
#define HTH 12                 // halo rows -2..9
#define FRAME_DW 1024          // 256 slots * 4 dwords = 4 KiB per frame
#define NFRAME 12              // ring of 12 frames = 48 KiB LDS

// Zero page for dummy/OOB chunks (device global: never written, stays 0).
__device__ __align__(16) float g_zeropage[8] = {0, 0, 0, 0, 0, 0, 0, 0};

typedef const __attribute__((address_space(1))) unsigned int* gptr_t;
typedef __attribute__((address_space(3))) unsigned int* lptr_t;
typedef float vf4 __attribute__((ext_vector_type(4)));

// out[t] = 0.8*out[t-1] + conv(x)[t-1]; out[0]=0 — conv and LI scan commute.
// Single-wave blocks, no barriers. Thread = 8 cols x 1 row (fewer LDS bytes
// per output). Chunk->slot map uses row stride 21 so b128 chunk reads spread
// across all bank groups (source pre-swizzle, LDS dest linear). Ring-12
// frames, 4-frame batches, counted vmcnt never touches stores.
__launch_bounds__(64)
__global__ void conv_li_kernel(const float* __restrict__ x,
                               const float* __restrict__ kern,
                               float* __restrict__ out) {
    __shared__ __align__(16) float lds[NFRAME * FRAME_DW];
    const int tid = threadIdx.x;
    const int bid = blockIdx.x;
    // 512 blocks over 8 XCDs (bijective): XCD k owns an 8-tile-row band ->
    // halo sharing (vertical and horizontal) stays in its L2 (~1.5MB live).
    const int vbid = (bid & 7) * 64 + (bid >> 3);
    const int bx = vbid & 7;       // 8 tiles across
    const int by = vbid >> 3;      // 64 tile rows

    // 5x5 kernel -> wave-uniform (SGPR) weights.
    float kw[25];
#pragma unroll
    for (int i = 0; i < 25; ++i)
        kw[i] = __int_as_float(__builtin_amdgcn_readfirstlane(__float_as_int(kern[i])));

    // Staging: issue k stages LDS slots k*64..k*64+63; lane L handles slot
    // s = k*64+L -> halo row s/21, chunk col s%21 (cc<18 real, else dummy).
    const float* src[4]; bool ok[4];
#pragma unroll
    for (int k = 0; k < 4; ++k) {
        int s = k * 64 + tid;
        int row = s / ROWSTRIDE, cc = s - row * ROWSTRIDE;
        int gy = by * TH + row - 2;
        int gx = bx * TW + cc * 4 - 4;
        ok[k] = (row < HTH) && (cc < ROWCHK) &&
                (gy >= 0) && (gy < IMG) && (gx >= 0) && (gx <= IMG - 4);
        src[k] = x + (size_t)(ok[k] ? gy : 0) * IMG + (ok[k] ? gx : 0);
    }

    auto GLDS = [&](int fi, int tf) {          // one frame = 4 glds issues
        float* fb = &lds[fi * FRAME_DW];
#pragma unroll
        for (int k = 0; k < 4; ++k) {
            const float* p = ok[k] ? src[k] + (size_t)tf * HW : g_zeropage;
            __builtin_amdgcn_global_load_lds((gptr_t)p, (lptr_t)(fb + k * 256), 16, 0, 0);
        }
    };
    auto BATCH = [&](int fbase, int f0) {      // 4 frames = 16 glds
#pragma unroll
        for (int j = 0; j < 4; ++j) {
            int tf = f0 + j; if (tf > T_STEPS - 1) tf = T_STEPS - 1;
            GLDS(fbase + j, tf);
        }
    };

    const int q = tid & 7;         // col-octet (8 out cols)
    const int rr = tid >> 3;       // out row within tile
    const size_t obase = (size_t)(by * TH + rr) * IMG + bx * TW + q * 8;

    float st[8] = {0.f, 0.f, 0.f, 0.f, 0.f, 0.f, 0.f, 0.f};

    auto STEP = [&](int fi, int t) {
        float acc[8] = {0.f, 0.f, 0.f, 0.f, 0.f, 0.f, 0.f, 0.f};
        const float* F = &lds[fi * FRAME_DW];
        // Window cols 8q-2..8q+9 live in chunks 2q..2q+3 of rows rr..rr+4
        // (stored cols -4..67; w[] dword i = col 8q-4+i; outputs use w[2..13]).
#pragma unroll
        for (int dy = 0; dy < 5; ++dy) {
            const float* L = F + ((rr + dy) * ROWSTRIDE + 2 * q) * 4;
            vf4 c0 = *(const vf4*)(L);
            vf4 c1 = *(const vf4*)(L + 4);
            vf4 c2 = *(const vf4*)(L + 8);
            vf4 c3 = *(const vf4*)(L + 12);
            const float w[16] = {c0.x, c0.y, c0.z, c0.w, c1.x, c1.y, c1.z, c1.w,
                                 c2.x, c2.y, c2.z, c2.w, c3.x, c3.y, c3.z, c3.w};
            const float k0 = kw[dy * 5 + 0], k1 = kw[dy * 5 + 1], k2 = kw[dy * 5 + 2];
            const float k3 = kw[dy * 5 + 3], k4 = kw[dy * 5 + 4];
#pragma unroll
            for (int o = 0; o < 8; ++o) {
                acc[o] = fmaf(k0, w[o + 2], acc[o]);
                acc[o] = fmaf(k1, w[o + 3], acc[o]);
                acc[o] = fmaf(k2, w[o + 4], acc[o]);
                acc[o] = fmaf(k3, w[o + 5], acc[o]);
                acc[o] = fmaf(k4, w[o + 6], acc[o]);
            }
        }
        vf4 lo = {st[0], st[1], st[2], st[3]};
        vf4 hi = {st[4], st[5], st[6], st[7]};
        float* op = out + (size_t)t * HW + obase;
        __builtin_nontemporal_store(lo, (vf4*)op);       // out[t] = S_{t-1}
        __builtin_nontemporal_store(hi, (vf4*)(op + 4));
#pragma unroll
        for (int o = 0; o < 8; ++o)
            st[o] = st[o] - 0.2f * st[o] + acc[o];       // S_t = 0.8*S + y[t]
    };

    // Prologue: batches B0,B1,B2 (frames 0..11) in flight.
    BATCH(0, 0);
    BATCH(4, 4);
    BATCH(8, 8);

    // g=0: newer-than-B0 = B1+B2 = 32.
    asm volatile("s_waitcnt vmcnt(32)" ::: "memory");
    STEP(0, 0); STEP(1, 1); STEP(2, 2); STEP(3, 3);
    BATCH(0, 12);
    // g=1: newer-than-B1 = B2(16)+s0(8)+B3(16) = 40.
    asm volatile("s_waitcnt vmcnt(40)" ::: "memory");
    STEP(4, 4); STEP(5, 5); STEP(6, 6); STEP(7, 7);
    BATCH(4, 16);
    // g>=2 steady state: newer-than-Bg = s(8)+B(16)+s(8)+B(16) = 48.
#pragma clang loop unroll(disable)
    for (int g = 2; g < 64; ++g) {
        const int bb = (g % 3) * 4;
        asm volatile("s_waitcnt vmcnt(48)" ::: "memory");
        const int t0 = g * 4;
        STEP(bb + 0, t0 + 0); STEP(bb + 1, t0 + 1);
        STEP(bb + 2, t0 + 2); STEP(bb + 3, t0 + 3);
        BATCH(bb, t0 + 12);
    }
}

extern "C" void kernel_launch(void* const* d_in, const int* in_sizes, int n_in,
                              void* d_out, int out_size, void* d_ws, size_t ws_size,
                              hipStream_t stream) {
    const float* x = (const float*)d_in[0];      // [256,1,512,512] f32
    const float* kern = (const float*)d_in[1];   // [5,5] f32
    float* out = (float*)d_out;                  // [256,1,512,512] f32

    conv_li_kernel<<<dim3(512), dim3(64), 0, stream>>>(x, kern, out);
}